// Round 1
// 1776.957 us; speedup vs baseline: 6.7518x; 6.7518x over previous
//
#include <hip/hip_runtime.h>
#include <math.h>

#define VOCAB 10000
#define DIM 64
#define LTOK 8
#define DGPT 256
#define NHEAD 4
#define NNODES 8192
#define NEDGES 2048
#define FDIM 512                 // LTOK*DIM
#define NROWS (NEDGES*LTOK)      // 16384

// ---------------- mask / labels ----------------
__global__ __launch_bounds__(256) void k_mask(const int* __restrict__ etok,
                                              const int* __restrict__ mrows,
                                              float* __restrict__ labels,
                                              int* __restrict__ mtok) {
    int i = blockIdx.x * 256 + threadIdx.x;     // < 16384
    int e = i >> 3;
    int t = etok[i];
    bool m = (mrows[e] != 0) && (t > 3);        // SPECIAL = {0,1,2,3}
    labels[i] = m ? (float)t : -100.0f;
    mtok[i] = m ? 4 : t;                        // MASK_ID = 4
}

// ---------------- embedding gather ----------------
__global__ __launch_bounds__(256) void k_embed(const int* __restrict__ tok,
                                               const float* __restrict__ emb,
                                               float* __restrict__ outf, int total) {
    int i = blockIdx.x * 256 + threadIdx.x;
    if (i >= total) return;
    int d = i & 63;
    int tl = i >> 6;
    outf[i] = emb[(size_t)tok[tl] * DIM + d];
}

// ---------------- eh = h[src] + h[dst] ----------------
__global__ __launch_bounds__(256) void k_eh(const float* __restrict__ h,
                                            const int* __restrict__ src,
                                            const int* __restrict__ dst,
                                            float* __restrict__ eh) {
    int i = blockIdx.x * 256 + threadIdx.x;     // < 2048*512
    int e = i >> 9; int f = i & 511;
    eh[i] = h[(size_t)src[e] * FDIM + f] + h[(size_t)dst[e] * FDIM + f];
}

// ---------------- generic tiled fp32 GEMM with fused epilogue ----------------
// out[M,N] = act(A[M,K] @ W[K,N] + bias[N] + res[resRow,N]) ; optional atomic scatter by dstIdx
// act: 0 none, 1 relu, 2 gelu(tanh approx)
__global__ __launch_bounds__(256) void gemm_kernel(
    const float* __restrict__ A, const float* __restrict__ W,
    const float* __restrict__ bias, const float* __restrict__ res,
    const int* __restrict__ resIdx, const int* __restrict__ dstIdx,
    float* __restrict__ out, int M, int N, int K, int act)
{
    __shared__ float As[16][68];   // [k][row] (+pad)
    __shared__ float Ws[16][68];   // [k][col] (+pad)
    int tid = threadIdx.x;
    int row0 = blockIdx.x * 64, col0 = blockIdx.y * 64;
    int ty = tid >> 4, tx = tid & 15;
    float acc[4][4] = {};
    int arow = tid >> 2;            // 0..63
    int acol4 = (tid & 3) * 4;      // 0,4,8,12
    int wrow = tid >> 4;            // 0..15
    int wcol4 = (tid & 15) * 4;

    for (int kc = 0; kc < K; kc += 16) {
        float4 av = *(const float4*)&A[(size_t)(row0 + arow) * K + kc + acol4];
        float4 wv = *(const float4*)&W[(size_t)(kc + wrow) * N + col0 + wcol4];
        __syncthreads();
        As[acol4 + 0][arow] = av.x;
        As[acol4 + 1][arow] = av.y;
        As[acol4 + 2][arow] = av.z;
        As[acol4 + 3][arow] = av.w;
        *(float4*)&Ws[wrow][wcol4] = wv;
        __syncthreads();
#pragma unroll
        for (int kk = 0; kk < 16; kk++) {
            float4 a4 = *(const float4*)&As[kk][ty * 4];
            float4 w4 = *(const float4*)&Ws[kk][tx * 4];
            float ar[4] = {a4.x, a4.y, a4.z, a4.w};
            float wr[4] = {w4.x, w4.y, w4.z, w4.w};
#pragma unroll
            for (int i = 0; i < 4; i++)
#pragma unroll
                for (int j = 0; j < 4; j++)
                    acc[i][j] += ar[i] * wr[j];
        }
    }

    const float c0 = 0.7978845608028654f, c1 = 0.044715f;
#pragma unroll
    for (int i = 0; i < 4; i++) {
        int row = row0 + ty * 4 + i;
        int rrow = resIdx ? resIdx[row] : row;
#pragma unroll
        for (int j = 0; j < 4; j++) {
            int col = col0 + tx * 4 + j;
            float v = acc[i][j];
            if (bias) v += bias[col];
            if (res)  v += res[(size_t)rrow * N + col];
            if (act == 1) v = fmaxf(v, 0.0f);
            else if (act == 2) { float t = v; v = 0.5f * t * (1.0f + tanhf(c0 * (t + c1 * t * t * t))); }
            if (dstIdx) atomicAdd(&out[(size_t)dstIdx[row] * N + col], v);
            else out[(size_t)row * N + col] = v;
        }
    }
}

// ---------------- per-edge attention (S=8, NH=4, hd=64) ----------------
__global__ __launch_bounds__(256) void k_attn(const float* __restrict__ q,
                                              const float* __restrict__ k,
                                              const float* __restrict__ v,
                                              float* __restrict__ o) {
    __shared__ float qs[8 * 256], ks[8 * 256], vs[8 * 256];
    __shared__ float sc[4 * 8 * 8];
    int b = blockIdx.x, t = threadIdx.x;
    const size_t base = (size_t)b * (8 * 256);
    for (int i = t; i < 2048; i += 256) { qs[i] = q[base + i]; ks[i] = k[base + i]; vs[i] = v[base + i]; }
    __syncthreads();
    {
        int h = t >> 6, sq = (t >> 3) & 7, sk = t & 7;
        float acc = 0.0f;
#pragma unroll
        for (int d = 0; d < 64; d++) acc += qs[sq * 256 + h * 64 + d] * ks[sk * 256 + h * 64 + d];
        sc[t] = acc * 0.125f;     // 1/sqrt(64)
    }
    __syncthreads();
    if (t < 32) {
        int h = t >> 3, sq = t & 7;
        float* r = &sc[h * 64 + sq * 8];
        float M = r[0];
        for (int i = 1; i < 8; i++) M = fmaxf(M, r[i]);
        float S = 0.0f, ex[8];
        for (int i = 0; i < 8; i++) { ex[i] = __expf(r[i] - M); S += ex[i]; }
        float inv = 1.0f / S;
        for (int i = 0; i < 8; i++) r[i] = ex[i] * inv;
    }
    __syncthreads();
    {
        int col = t; int h = col >> 6;
#pragma unroll
        for (int sq = 0; sq < 8; sq++) {
            float a = 0.0f;
#pragma unroll
            for (int sk = 0; sk < 8; sk++) a += sc[h * 64 + sq * 8 + sk] * vs[sk * 256 + col];
            o[base + sq * 256 + col] = a;
        }
    }
}

// ---------------- logits = y @ emb^T, written into probs buffer ----------------
// Thread owns ONE vocab column: its emb row lives in 64 VGPRs for the whole kernel.
// Y rows staged in LDS, read as all-lane-broadcast float4 (bank-conflict-free).
// Stores are lane-contiguous along vocab -> fully coalesced.
// grid = (NROWS/512, ceil(VOCAB/256)) = (32, 40) = 1280 blocks = 5 blocks/CU.
__global__ __launch_bounds__(256) void k_logits(const float* __restrict__ Y,
                                                const float* __restrict__ emb,
                                                float* __restrict__ probs) {
    __shared__ float ys[128][64];   // 32 KB
    int t = threadIdx.x;
    int v = blockIdx.y * 256 + t;
    bool vok = v < VOCAB;

    float er[64];
    {
        const float4* ep = (const float4*)&emb[(size_t)(vok ? v : 0) * DIM];
#pragma unroll
        for (int i = 0; i < 16; i++) {
            float4 e4 = ep[i];
            er[4*i+0] = e4.x; er[4*i+1] = e4.y; er[4*i+2] = e4.z; er[4*i+3] = e4.w;
        }
    }

    int r0 = blockIdx.x * 512;
    for (int c = 0; c < 512; c += 128) {
        __syncthreads();           // protect previous chunk's reads
        // stage 128 rows x 64 of Y (coalesced, 8 float4 per thread)
#pragma unroll
        for (int q = 0; q < 8; q++) {
            int fidx = q * 256 + t;            // 0..2047
            int row = fidx >> 4;               // 0..127
            int k4 = (fidx & 15) * 4;          // 0..60
            *(float4*)&ys[row][k4] = *(const float4*)&Y[(size_t)(r0 + c + row) * DIM + k4];
        }
        __syncthreads();

        for (int r = 0; r < 128; r += 4) {
            float a0 = 0.f, a1 = 0.f, a2 = 0.f, a3 = 0.f;
#pragma unroll
            for (int kk = 0; kk < 16; kk++) {
                float4 y0 = *(const float4*)&ys[r + 0][kk * 4];
                float4 y1 = *(const float4*)&ys[r + 1][kk * 4];
                float4 y2 = *(const float4*)&ys[r + 2][kk * 4];
                float4 y3 = *(const float4*)&ys[r + 3][kk * 4];
                float e0 = er[4*kk+0], e1 = er[4*kk+1], e2 = er[4*kk+2], e3 = er[4*kk+3];
                a0 += y0.x * e0; a0 += y0.y * e1; a0 += y0.z * e2; a0 += y0.w * e3;
                a1 += y1.x * e0; a1 += y1.y * e1; a1 += y1.z * e2; a1 += y1.w * e3;
                a2 += y2.x * e0; a2 += y2.y * e1; a2 += y2.z * e2; a2 += y2.w * e3;
                a3 += y3.x * e0; a3 += y3.y * e1; a3 += y3.z * e2; a3 += y3.w * e3;
            }
            if (vok) {
                size_t base = (size_t)(r0 + c + r) * VOCAB + v;
                probs[base]             = a0;
                probs[base +     VOCAB] = a1;
                probs[base + 2 * VOCAB] = a2;
                probs[base + 3 * VOCAB] = a3;
            }
        }
    }
}

// ---------------- in-place row softmax over VOCAB (row cached in LDS) ----------------
__global__ __launch_bounds__(256) void k_softmax(float* __restrict__ probs) {
    __shared__ float4 sdata[VOCAB / 4];   // 2500 float4 = 40000 B
    __shared__ float wred[8];
    int t = threadIdx.x;
    float4* prow = (float4*)&probs[(size_t)blockIdx.x * VOCAB];

    // pass 1: load + local max
    float m = -1e30f;
#pragma unroll
    for (int i = 0; i < 10; i++) {
        int j = t + 256 * i;
        if (j < VOCAB / 4) {
            float4 v4 = prow[j];
            sdata[j] = v4;
            m = fmaxf(fmaxf(fmaxf(m, v4.x), v4.y), fmaxf(v4.z, v4.w));
        }
    }
#pragma unroll
    for (int off = 32; off; off >>= 1) m = fmaxf(m, __shfl_xor(m, off, 64));
    if ((t & 63) == 0) wred[t >> 6] = m;
    __syncthreads();
    float M = fmaxf(fmaxf(wred[0], wred[1]), fmaxf(wred[2], wred[3]));

    // pass 2: exp + local sum (store exp back to LDS)
    float s = 0.0f;
#pragma unroll
    for (int i = 0; i < 10; i++) {
        int j = t + 256 * i;
        if (j < VOCAB / 4) {
            float4 v4 = sdata[j];
            v4.x = __expf(v4.x - M); v4.y = __expf(v4.y - M);
            v4.z = __expf(v4.z - M); v4.w = __expf(v4.w - M);
            sdata[j] = v4;
            s += v4.x + v4.y + v4.z + v4.w;
        }
    }
#pragma unroll
    for (int off = 32; off; off >>= 1) s += __shfl_xor(s, off, 64);
    if ((t & 63) == 0) wred[4 + (t >> 6)] = s;
    __syncthreads();
    float Sinv = 1.0f / (wred[4] + wred[5] + wred[6] + wred[7]);

    // pass 3: scale + store
#pragma unroll
    for (int i = 0; i < 10; i++) {
        int j = t + 256 * i;
        if (j < VOCAB / 4) {
            float4 v4 = sdata[j];
            v4.x *= Sinv; v4.y *= Sinv; v4.z *= Sinv; v4.w *= Sinv;
            prow[j] = v4;
        }
    }
}

extern "C" void kernel_launch(void* const* d_in, const int* in_sizes, int n_in,
                              void* d_out, int out_size, void* d_ws, size_t ws_size,
                              hipStream_t stream) {
    const int* node_tokens = (const int*)d_in[0];
    const int* edge_tokens = (const int*)d_in[1];
    const int* edge_index  = (const int*)d_in[2];
    const int* mask_rows   = (const int*)d_in[3];   // bool passed as int32
    const float* emb    = (const float*)d_in[4];
    const float* W_msg  = (const float*)d_in[5];
    const float* W_node = (const float*)d_in[6];
    const float* lc1_w  = (const float*)d_in[7];
    const float* lc1_b  = (const float*)d_in[8];
    const float* lc2_w  = (const float*)d_in[9];
    const float* lc2_b  = (const float*)d_in[10];
    const float* Wq     = (const float*)d_in[11];
    const float* Wk     = (const float*)d_in[12];
    const float* Wv     = (const float*)d_in[13];
    const float* Wo     = (const float*)d_in[14];
    const float* Wf1    = (const float*)d_in[15];
    const float* Wf2    = (const float*)d_in[16];

    const int* src = edge_index;
    const int* dst = edge_index + NEDGES;

    float* labels = (float*)d_out;
    float* probs  = labels + NROWS;

    float* ws = (float*)d_ws;
    float* X   = ws;                  // [8192,512]
    float* E_  = X   + 4194304;       // [2048,512]
    float* AGG = E_  + 1048576;       // [8192,512], becomes H in-place
    float* EH  = AGG + 4194304;       // [2048,512] == z rows [16384,64]
    float* Z1  = EH  + 1048576;       // [16384,256]
    float* Q_  = Z1  + 4194304;
    float* K_  = Q_  + 4194304;
    float* Vv  = K_  + 4194304;
    float* O_  = Vv  + 4194304;
    float* X2  = O_  + 4194304;
    float* U_  = X2  + 4194304;       // [16384,1024]
    float* Y2  = U_  + 16777216;      // [16384,256]
    float* Y_  = Y2  + 4194304;       // [16384,64]
    int*  MTOK = (int*)(Y_ + 1048576);

    // zero agg for scatter-add
    hipMemsetAsync(AGG, 0, (size_t)NNODES * FDIM * sizeof(float), stream);

    // masking + labels
    k_mask<<<NROWS / 256, 256, 0, stream>>>(edge_tokens, mask_rows, labels, MTOK);

    // embeddings
    k_embed<<<(NNODES * FDIM) / 256, 256, 0, stream>>>(node_tokens, emb, X, NNODES * FDIM);
    k_embed<<<(NEDGES * FDIM) / 256, 256, 0, stream>>>(MTOK, emb, E_, NEDGES * FDIM);

    // msg = relu(e @ W_msg + x[src]); scatter-add to agg[dst]
    gemm_kernel<<<dim3(NEDGES / 64, FDIM / 64), 256, 0, stream>>>(
        E_, W_msg, nullptr, X, src, dst, AGG, NEDGES, FDIM, FDIM, 1);

    // h = relu(x @ W_node + agg)   (in-place into AGG)
    gemm_kernel<<<dim3(NNODES / 64, FDIM / 64), 256, 0, stream>>>(
        X, W_node, nullptr, AGG, nullptr, nullptr, AGG, NNODES, FDIM, FDIM, 1);

    // eh = h[src] + h[dst]
    k_eh<<<(NEDGES * FDIM) / 256, 256, 0, stream>>>(AGG, src, dst, EH);

    // z1 = eh @ lc1_w + lc1_b    ([16384,64] @ [64,256])
    gemm_kernel<<<dim3(NROWS / 64, DGPT / 64), 256, 0, stream>>>(
        EH, lc1_w, lc1_b, nullptr, nullptr, nullptr, Z1, NROWS, DGPT, DIM, 0);

    // q,k,v projections
    gemm_kernel<<<dim3(NROWS / 64, DGPT / 64), 256, 0, stream>>>(
        Z1, Wq, nullptr, nullptr, nullptr, nullptr, Q_, NROWS, DGPT, DGPT, 0);
    gemm_kernel<<<dim3(NROWS / 64, DGPT / 64), 256, 0, stream>>>(
        Z1, Wk, nullptr, nullptr, nullptr, nullptr, K_, NROWS, DGPT, DGPT, 0);
    gemm_kernel<<<dim3(NROWS / 64, DGPT / 64), 256, 0, stream>>>(
        Z1, Wv, nullptr, nullptr, nullptr, nullptr, Vv, NROWS, DGPT, DGPT, 0);

    // attention
    k_attn<<<NEDGES, 256, 0, stream>>>(Q_, K_, Vv, O_);

    // x2 = z1 + o @ Wo
    gemm_kernel<<<dim3(NROWS / 64, DGPT / 64), 256, 0, stream>>>(
        O_, Wo, nullptr, Z1, nullptr, nullptr, X2, NROWS, DGPT, DGPT, 0);

    // u = gelu(x2 @ Wf1)
    gemm_kernel<<<dim3(NROWS / 64, (4 * DGPT) / 64), 256, 0, stream>>>(
        X2, Wf1, nullptr, nullptr, nullptr, nullptr, U_, NROWS, 4 * DGPT, DGPT, 2);

    // y2 = x2 + u @ Wf2
    gemm_kernel<<<dim3(NROWS / 64, DGPT / 64), 256, 0, stream>>>(
        U_, Wf2, nullptr, X2, nullptr, nullptr, Y2, NROWS, DGPT, 4 * DGPT, 0);

    // y = y2 @ lc2_w + lc2_b
    gemm_kernel<<<dim3(NROWS / 64, DIM / 64), 256, 0, stream>>>(
        Y2, lc2_w, lc2_b, nullptr, nullptr, nullptr, Y_, NROWS, DIM, DGPT, 0);

    // logits into probs buffer (one pass), then in-place row softmax
    k_logits<<<dim3(NROWS / 512, (VOCAB + 255) / 256), 256, 0, stream>>>(Y_, emb, probs);
    k_softmax<<<NROWS, 256, 0, stream>>>(probs);
}